// Round 17
// baseline (15.466 us; speedup 1.0000x reference)
//
#include <hip/hip_runtime.h>
#include <math.h>

// Problem geometry (fixed by the reference)
#define NB 2
#define NVOICE 8
#define NN (NB * NVOICE)   // 16 series
#define NH 64              // harmonics
#define NF 500             // frames
#define NT 32000           // samples
#define NPAIR 250          // one PAIR of 64-sample windows per wave
#define WIN 64

// ---- compile-time Hann window table (f64 Taylor cos, rounded to f32) ----
constexpr double kPIO2 = 1.5707963267948966;
constexpr double d_cos_red(double r) {
    double r2 = r * r, term = 1.0, sum = 1.0;
    for (int k = 1; k <= 12; ++k) { term *= -r2 / (double)((2 * k - 1) * (2 * k)); sum += term; }
    return sum;
}
constexpr double d_sin_red(double r) {
    double r2 = r * r, term = r, sum = r;
    for (int k = 1; k <= 12; ++k) { term *= -r2 / (double)((2 * k) * (2 * k + 1)); sum += term; }
    return sum;
}
constexpr double d_cos(double x) {
    int k = 0; double r = x;
    while (r > kPIO2 * 0.5) { r -= kPIO2; ++k; }
    switch (k & 3) {
        case 0: return d_cos_red(r);
        case 1: return -d_sin_red(r);
        case 2: return -d_cos_red(r);
        default: return d_sin_red(r);
    }
}
struct WinT { float wA[64]; float wB[64]; };
constexpr WinT make_win() {
    WinT w{};
    for (int j = 0; j < 64; ++j) {
        float aA = (float)6.283185307179586 * (float)j * 0.0078125f;
        float aB = (float)6.283185307179586 * (float)(j + 64) * 0.0078125f;
        w.wA[j] = 0.5f - 0.5f * (float)d_cos((double)aA);   // win[r]    -> weights frame q+1
        w.wB[j] = 0.5f - 0.5f * (float)d_cos((double)aB);   // win[64+r] -> weights frame q
    }
    return w;
}
constexpr WinT WT = make_win();

// DPP helpers
template<int CTRL, int RMASK>
static __device__ __forceinline__ float dpp0_add(float x) {
    int y = __builtin_amdgcn_update_dpp(0, __float_as_int(x), CTRL, RMASK, 0xF, true);
    return x + __int_as_float(y);
}
// Inclusive 64-lane prefix sum (Hillis-Steele via DPP)
static __device__ __forceinline__ float wave_incl_scan(float x) {
    x = dpp0_add<0x111, 0xF>(x);   // row_shr:1
    x = dpp0_add<0x112, 0xF>(x);   // row_shr:2
    x = dpp0_add<0x114, 0xF>(x);   // row_shr:4
    x = dpp0_add<0x118, 0xF>(x);   // row_shr:8
    x = dpp0_add<0x142, 0xa>(x);   // row_bcast:15 -> rows 1,3
    x = dpp0_add<0x143, 0xc>(x);   // row_bcast:31 -> rows 2,3
    return x;
}
// Full 64-lane sums broadcast to all lanes (prologue only)
static __device__ __forceinline__ float wave_sum_all_f(float x) {
    #pragma unroll
    for (int m = 1; m < 64; m <<= 1) x += __shfl_xor(x, m, 64);
    return x;
}
static __device__ __forceinline__ double wave_sum_all_d(double x) {
    #pragma unroll
    for (int m = 1; m < 64; m <<= 1) x += __shfl_xor(x, m, 64);
    return x;
}

// One 64-sample window: lane l = sample. Returns per-lane inclusive scan of the
// base-freq envelope (lane 63 = window total, used to chain D to next window).
static __device__ __forceinline__ float syn_window(int l,
                                                   float vA, float vB, float vC,
                                                   int edgeLo, int edgeHi,
                                                   double Dstart, float wAv, float wBv,
                                                   const float2* __restrict__ pbRow,
                                                   float* __restrict__ vsDst) {
    bool mlo   = (l < 32);
    bool mEdge = (edgeLo && mlo) || (edgeHi && !mlo);
    float wy = (float)(mlo ? (2 * l + 65) : (2 * l - 63)) * 0.0078125f;
    float wx = 1.0f - wy;
    if (mEdge) { wx = 1.0f; wy = 0.0f; }     // clamped lerp == fl(vB*k) exactly
    float vLo0 = mEdge ? vB : (mlo ? vA : vB);
    float vLo1 = mEdge ? vB : (mlo ? vB : vC);

    // in-window base-envelope inclusive scan (phase-tolerant)
    float feB = __fadd_rn(__fmul_rn(vLo0, wx), __fmul_rn(vLo1, wy));
    float scanB = wave_incl_scan(feB);

    // per-lane fundamental phase (revolutions), f64 fract for precision
    float phiF;
    {
        double Phid = (Dstart + (double)scanB) * (1.0 / 16000.0);
        Phid -= floor(Phid);
        phiF = (float)Phid;
    }
    float sp, cp;
    asm("v_sin_f32 %0, %1" : "=v"(sp) : "v"(phiF));   // sin(2pi*phi)
    asm("v_cos_f32 %0, %1" : "=v"(cp) : "v"(phiF));   // cos(2pi*phi)
    float c2 = __fadd_rn(cp, cp);

    // live-harmonic bounds via rcp (guard bands >> 2-ulp rcp error; exact mask in band 2)
    float mxf = fmaxf(fmaxf(vA, vB), vC);
    float mnf = fminf(fminf(vA, vB), vC);
    float rcm, rcx;
    asm("v_rcp_f32 %0, %1" : "=v"(rcm) : "v"(mnf));
    asm("v_rcp_f32 %0, %1" : "=v"(rcx) : "v"(mxf));
    int hmax = min(64, (int)(__fmul_rn(8000.5f, rcm)));
    int hA   = min(hmax, (int)(__fmul_rn(7999.9f, rcx)));
    hmax = __builtin_amdgcn_readfirstlane(hmax);
    hA   = __builtin_amdgcn_readfirstlane(hA);

    float accA = 0.0f, accB = 0.0f;          // audio = wA*accA + wB*accB (factored amp)
    float skm1 = 0.0f, sk = sp;              // s_0 = 0, s_1 = sin(theta)
    int hh = 0;
    #pragma unroll 4
    for (; hh < hA; ++hh) {                  // fe <= 8000 guaranteed: no mask
        float2 a = pbRow[hh];
        accA = __fmaf_rn(sk, a.x, accA);
        accB = __fmaf_rn(sk, a.y, accB);
        float sn = __fmaf_rn(c2, sk, -skm1); // Chebyshev step
        skm1 = sk; sk = sn;
    }
    float kfv = (float)(hA + 1);
    #pragma unroll 4
    for (; hh < hmax; ++hh, kfv += 1.0f) {   // crossing band: bit-exact fe + mask
        float2 a = pbRow[hh];
        float h0 = __fmul_rn(vLo0, kfv), h1 = __fmul_rn(vLo1, kfv);
        float fe = __fadd_rn(__fmul_rn(h0, wx), __fmul_rn(h1, wy));
        float sv = (fe > 8000.0f) ? 0.0f : sk;   // strict >, bit-exact fe
        accA = __fmaf_rn(sv, a.x, accA);
        accB = __fmaf_rn(sv, a.y, accB);
        float sn = __fmaf_rn(c2, sk, -skm1);
        skm1 = sk; sk = sn;
    }
    *vsDst = __fadd_rn(__fmul_rn(accA, wAv), __fmul_rn(accB, wBv));
    return scanB;
}

// Fused kernel: block = (b, window-pair p); 512 thr = 8 voices x 64 lanes.
// Wave handles windows q0=2p, q1=2p+1. D0 by exact f64 closed form; D1 chains
// via the telescoping identity D(64(q+1)) = D(64q) + window-sum(feB).
__global__ __launch_bounds__(512) void ksyn_all(const float* __restrict__ freqs,
                                                const float* __restrict__ harms,
                                                const float* __restrict__ amps,
                                                float* __restrict__ out) {
    int p = blockIdx.x % NPAIR;
    int b = blockIdx.x / NPAIR;
    int tid = threadIdx.x;
    int v = tid >> 6, l = tid & 63;
    int n = (b << 3) + v;

    __shared__ float2 pb0[NVOICE][NH];       // window0 {a1, a0}
    __shared__ float2 pb1[NVOICE][NH];       // window1 {a2, a1}
    __shared__ float vsum[NVOICE][2 * WIN];  // per-voice audio (128 samples)

    int q0 = p << 1, q1 = q0 + 1;
    int f2 = (q1 + 1 < NF) ? q1 + 1 : NF - 1;
    const float* __restrict__ fr = freqs + n * NF;

    // ---- wave-uniform f64 frame prefix D0 (coalesced lane-batches, masked j<q0)
    double D0;
    {
        double accd = 0.0;
        for (int j0 = 0; j0 < q0; j0 += 64) {
            int j = j0 + l;
            float fv = (j < q0) ? fr[j] : 0.0f;
            accd += (double)fv;
        }
        double S = wave_sum_all_d(accd);
        D0 = 64.0 * S;
        if (q0 > 0) D0 += 8.0 * ((double)fr[q0] - (double)fr[q0 - 1]);
    }

    // ---- normalization for frames q0, q1, f2 (bit-exact mask, butterfly denom)
    float fq0 = fr[q0], fq1 = fr[q1], fq2 = fr[f2];
    {
        float kf = (float)(l + 1);
        const float* __restrict__ hb = harms + ((size_t)n * NH + l) * NF;
        float hm0 = hb[q0], hm1 = hb[q1], hm2 = hb[f2];
        hm0 = (__fmul_rn(fq0, kf) > 8000.0f) ? 0.0f : hm0;
        hm1 = (__fmul_rn(fq1, kf) > 8000.0f) ? 0.0f : hm1;
        hm2 = (__fmul_rn(fq2, kf) > 8000.0f) ? 0.0f : hm2;
        float d0 = wave_sum_all_f(hm0);
        float d1 = wave_sum_all_f(hm1);
        float d2 = wave_sum_all_f(hm2);
        d0 = (d0 == 0.0f) ? 1e-7f : d0;
        d1 = (d1 == 0.0f) ? 1e-7f : d1;
        d2 = (d2 == 0.0f) ? 1e-7f : d2;
        float va0 = amps[n * NF + q0], va1 = amps[n * NF + q1], va2 = amps[n * NF + f2];
        float a0 = __fmul_rn(va0, __fdiv_rn(hm0, d0));
        float a1 = __fmul_rn(va1, __fdiv_rn(hm1, d1));
        float a2 = __fmul_rn(va2, __fdiv_rn(hm2, d2));
        pb0[v][l] = make_float2(a1, a0);
        pb1[v][l] = make_float2(a2, a1);
        // wave-private LDS rows; DS ops retire in order per wave -> no block barrier
    }

    float wAv = WT.wA[l], wBv = WT.wB[l];
    float vA0 = fr[(q0 > 0) ? q0 - 1 : 0];

    // ---- window 0 (q0): possible low edge at q0==0
    float scan0 = syn_window(l, vA0, fq0, fq1, (q0 == 0), 0,
                             D0, wAv, wBv, pb0[v], &vsum[v][l]);
    // ---- chain D to window 1 via lane-63 window total (phase-tolerant)
    double D1 = D0 + (double)__int_as_float(
                    __builtin_amdgcn_readlane(__float_as_int(scan0), 63));
    // ---- window 1 (q1): possible high edge at q1==NF-1
    syn_window(l, fq0, fq1, fq2, 0, (q1 == NF - 1),
               D1, wAv, wBv, pb1[v], &vsum[v][WIN + l]);

    __syncthreads();

    if (tid < 2 * WIN) {
        float s8 = 0.0f;
        #pragma unroll
        for (int vv = 0; vv < NVOICE; ++vv) s8 = __fadd_rn(s8, vsum[vv][tid]);
        out[(size_t)b * NT + (p << 7) + tid] = __fmul_rn(0.02f, s8);
    }
}

extern "C" void kernel_launch(void* const* d_in, const int* in_sizes, int n_in,
                              void* d_out, int out_size, void* d_ws, size_t ws_size,
                              hipStream_t stream) {
    (void)in_sizes; (void)n_in; (void)out_size; (void)d_ws; (void)ws_size;
    const float* freqs = (const float*)d_in[0];   // (2,8,500)
    const float* harms = (const float*)d_in[1];   // (2,8,64,500)
    const float* amps  = (const float*)d_in[2];   // (2,8,500)
    float* out = (float*)d_out;                   // (2,32000)

    hipLaunchKernelGGL(ksyn_all, dim3(NB * NPAIR), dim3(512), 0, stream,
                       freqs, harms, amps, out);
}

// Round 18
// 14.058 us; speedup vs baseline: 1.1001x; 1.1001x over previous
//
#include <hip/hip_runtime.h>
#include <math.h>

// Problem geometry (fixed by the reference)
#define NB 2
#define NVOICE 8
#define NN (NB * NVOICE)   // 16 series
#define NH 64              // harmonics
#define NF 500             // frames
#define NT 32000           // samples
#define NWIN 500           // one 64-sample window per block
#define WIN 64

// ---- compile-time Hann window table (f64 Taylor cos, rounded to f32) ----
constexpr double kPIO2 = 1.5707963267948966;
constexpr double d_cos_red(double r) {
    double r2 = r * r, term = 1.0, sum = 1.0;
    for (int k = 1; k <= 12; ++k) { term *= -r2 / (double)((2 * k - 1) * (2 * k)); sum += term; }
    return sum;
}
constexpr double d_sin_red(double r) {
    double r2 = r * r, term = r, sum = r;
    for (int k = 1; k <= 12; ++k) { term *= -r2 / (double)((2 * k) * (2 * k + 1)); sum += term; }
    return sum;
}
constexpr double d_cos(double x) {
    int k = 0; double r = x;
    while (r > kPIO2 * 0.5) { r -= kPIO2; ++k; }
    switch (k & 3) {
        case 0: return d_cos_red(r);
        case 1: return -d_sin_red(r);
        case 2: return -d_cos_red(r);
        default: return d_sin_red(r);
    }
}
struct WinT { float wA[64]; float wB[64]; };
constexpr WinT make_win() {
    WinT w{};
    for (int j = 0; j < 64; ++j) {
        float aA = (float)6.283185307179586 * (float)j * 0.0078125f;
        float aB = (float)6.283185307179586 * (float)(j + 64) * 0.0078125f;
        w.wA[j] = 0.5f - 0.5f * (float)d_cos((double)aA);   // win[r]    -> weights frame q+1
        w.wB[j] = 0.5f - 0.5f * (float)d_cos((double)aB);   // win[64+r] -> weights frame q
    }
    return w;
}
constexpr WinT WT = make_win();

// DPP helpers
template<int CTRL, int RMASK>
static __device__ __forceinline__ float dpp0_add(float x) {
    int y = __builtin_amdgcn_update_dpp(0, __float_as_int(x), CTRL, RMASK, 0xF, true);
    return x + __int_as_float(y);
}
// Inclusive 64-lane prefix sum (Hillis-Steele via DPP)
static __device__ __forceinline__ float wave_incl_scan(float x) {
    x = dpp0_add<0x111, 0xF>(x);   // row_shr:1
    x = dpp0_add<0x112, 0xF>(x);   // row_shr:2
    x = dpp0_add<0x114, 0xF>(x);   // row_shr:4
    x = dpp0_add<0x118, 0xF>(x);   // row_shr:8
    x = dpp0_add<0x142, 0xa>(x);   // row_bcast:15 -> rows 1,3
    x = dpp0_add<0x143, 0xc>(x);   // row_bcast:31 -> rows 2,3
    return x;
}
// Full 64-lane sums broadcast to all lanes (prologue only)
static __device__ __forceinline__ float wave_sum_all_f(float x) {
    #pragma unroll
    for (int m = 1; m < 64; m <<= 1) x += __shfl_xor(x, m, 64);
    return x;
}
static __device__ __forceinline__ double wave_sum_all_d(double x) {
    #pragma unroll
    for (int m = 1; m < 64; m <<= 1) x += __shfl_xor(x, m, 64);
    return x;
}

// Fused kernel: block = (b, window q); 512 thr = 8 voices x 64 lanes.
// Phase: exact f64 closed form D(64q) = 64*Sum_{j<q} fr[j] + 8*(fr[q]-fr[q-1]);
// per-harmonic sin via Chebyshev recurrence s_k = 2cos(theta)*s_{k-1} - s_{k-2}.
__global__ __launch_bounds__(512) void ksyn_all(const float* __restrict__ freqs,
                                                const float* __restrict__ harms,
                                                const float* __restrict__ amps,
                                                float* __restrict__ out) {
    int q = blockIdx.x % NWIN;
    int b = blockIdx.x / NWIN;
    int tid = threadIdx.x;
    int v = tid >> 6, l = tid & 63;
    int n = (b << 3) + v;

    __shared__ float2 pb[NVOICE][NH];      // {a1, a0} per (voice,h)
    __shared__ float vsum[NVOICE][WIN];    // per-voice audio

    int f1 = (q + 1 < NF) ? q + 1 : NF - 1;
    const float* __restrict__ fr = freqs + n * NF;

    // ---- wave-uniform f64 frame prefix D0 (coalesced lane-batches, masked j<q)
    double D0;
    {
        double accd = 0.0;
        for (int j0 = 0; j0 < q; j0 += 64) {
            int j = j0 + l;
            float fv = (j < q) ? fr[j] : 0.0f;
            accd += (double)fv;
        }
        double S = wave_sum_all_d(accd);
        D0 = 64.0 * S;
        if (q > 0) D0 += 8.0 * ((double)fr[q] - (double)fr[q - 1]);
    }

    // ---- prologue, lane role = h: normalization (bit-exact mask, butterfly denom)
    {
        int h = l;
        float kf = (float)(h + 1);
        const float* __restrict__ hb = harms + ((size_t)n * NH + h) * NF;
        float fq0 = fr[q], fq1 = fr[f1];
        float hm0 = hb[q], hm1 = hb[f1];
        hm0 = (__fmul_rn(fq0, kf) > 8000.0f) ? 0.0f : hm0;
        hm1 = (__fmul_rn(fq1, kf) > 8000.0f) ? 0.0f : hm1;
        float d0 = wave_sum_all_f(hm0), d1 = wave_sum_all_f(hm1);
        d0 = (d0 == 0.0f) ? 1e-7f : d0;
        d1 = (d1 == 0.0f) ? 1e-7f : d1;
        float va0 = amps[n * NF + q], va1 = amps[n * NF + f1];
        float a0 = __fmul_rn(va0, __fdiv_rn(hm0, d0));
        float a1 = __fmul_rn(va1, __fdiv_rn(hm1, d1));
        pb[v][h] = make_float2(a1, a0);
        // wave-private LDS row; DS ops retire in order per wave -> no block barrier
    }

    // ---- main, lane role = sample t = 64q + l ----
    float vAu = fr[(q > 0) ? q - 1 : 0];     // lane-uniform
    float vBu = fr[q];
    float vCu = fr[f1];
    bool mlo   = (l < 32);
    bool mEdge = (q == 0 && mlo) || (q == NF - 1 && !mlo);
    float wy = (float)(mlo ? (2 * l + 65) : (2 * l - 63)) * 0.0078125f;
    float wx = 1.0f - wy;
    if (mEdge) { wx = 1.0f; wy = 0.0f; }     // clamped lerp == fl(vB*k) exactly
    float vLo0 = mEdge ? vBu : (mlo ? vAu : vBu);
    float vLo1 = mEdge ? vBu : (mlo ? vBu : vCu);
    float wA = WT.wA[l], wB = WT.wB[l];

    // in-window base-envelope inclusive scan (phase-tolerant)
    float feB = __fadd_rn(__fmul_rn(vLo0, wx), __fmul_rn(vLo1, wy));
    float scanB = wave_incl_scan(feB);

    // per-lane fundamental phase (revolutions), f64 fract for precision
    float phiF;
    {
        double Phid = (D0 + (double)scanB) * (1.0 / 16000.0);
        Phid -= floor(Phid);
        phiF = (float)Phid;
    }
    float sp, cp;
    asm("v_sin_f32 %0, %1" : "=v"(sp) : "v"(phiF));   // sin(2pi*phi)
    asm("v_cos_f32 %0, %1" : "=v"(cp) : "v"(phiF));   // cos(2pi*phi)
    float c2 = __fadd_rn(cp, cp);

    // live-harmonic bounds (conservative guards; exact mask still applied in band)
    float mxf = fmaxf(fmaxf(vAu, vBu), vCu);
    float mnf = fminf(fminf(vAu, vBu), vCu);
    int hmax = min(64, (int)(__fdiv_rn(8000.5f, mnf)));
    int hA   = min(hmax, (int)(__fdiv_rn(7999.96f, mxf)));
    hmax = __builtin_amdgcn_readfirstlane(hmax);
    hA   = __builtin_amdgcn_readfirstlane(hA);

    const float2* __restrict__ pbRow = pb[v];
    float accA = 0.0f, accB = 0.0f;          // audio = wA*accA + wB*accB (factored amp)
    float skm1 = 0.0f, sk = sp;              // s_0 = 0, s_1 = sin(theta)
    int hh = 0;
    #pragma unroll 4
    for (; hh < hA; ++hh) {                  // fe <= 8000 guaranteed: no mask
        float2 a = pbRow[hh];
        accA = __fmaf_rn(sk, a.x, accA);
        accB = __fmaf_rn(sk, a.y, accB);
        float sn = __fmaf_rn(c2, sk, -skm1); // Chebyshev step
        skm1 = sk; sk = sn;
    }
    float kfv = (float)(hA + 1);
    #pragma unroll 4
    for (; hh < hmax; ++hh, kfv += 1.0f) {   // crossing band: bit-exact fe + mask
        float2 a = pbRow[hh];
        float h0 = __fmul_rn(vLo0, kfv), h1 = __fmul_rn(vLo1, kfv);
        float fe = __fadd_rn(__fmul_rn(h0, wx), __fmul_rn(h1, wy));
        float sv = (fe > 8000.0f) ? 0.0f : sk;   // strict >, bit-exact fe
        accA = __fmaf_rn(sv, a.x, accA);
        accB = __fmaf_rn(sv, a.y, accB);
        float sn = __fmaf_rn(c2, sk, -skm1);
        skm1 = sk; sk = sn;
    }
    vsum[v][l] = __fadd_rn(__fmul_rn(accA, wA), __fmul_rn(accB, wB));
    __syncthreads();

    if (tid < WIN) {
        float s8 = 0.0f;
        #pragma unroll
        for (int vv = 0; vv < NVOICE; ++vv) s8 = __fadd_rn(s8, vsum[vv][tid]);
        out[(size_t)b * NT + (q << 6) + tid] = __fmul_rn(0.02f, s8);
    }
}

extern "C" void kernel_launch(void* const* d_in, const int* in_sizes, int n_in,
                              void* d_out, int out_size, void* d_ws, size_t ws_size,
                              hipStream_t stream) {
    (void)in_sizes; (void)n_in; (void)out_size; (void)d_ws; (void)ws_size;
    const float* freqs = (const float*)d_in[0];   // (2,8,500)
    const float* harms = (const float*)d_in[1];   // (2,8,64,500)
    const float* amps  = (const float*)d_in[2];   // (2,8,500)
    float* out = (float*)d_out;                   // (2,32000)

    hipLaunchKernelGGL(ksyn_all, dim3(NB * NWIN), dim3(512), 0, stream,
                       freqs, harms, amps, out);
}